// Round 18
// baseline (431.784 us; speedup 1.0000x reference)
//
#include <hip/hip_runtime.h>
#include <hip/hip_bf16.h>
#include <math.h>

typedef __attribute__((ext_vector_type(8))) short short8;
typedef __attribute__((ext_vector_type(4))) float f32x4;

#define NB 4
#define NS 2048
#define ND 1024
#define NH 16
#define NDK 64
#define NF 4096
#define NM (NB*NS)   // 8192 rows total

// 1/sqrt(DK) * log2(e): scores come out of QK^T already in log2 domain
#define QSCALE 0.18033688f

__device__ __forceinline__ unsigned short f2b(float f) {
  union { __hip_bfloat16 h; unsigned short u; } c;
  c.h = __float2bfloat16(f);
  return c.u;
}

__device__ __forceinline__ float b2f(unsigned short u) {
  union { float f; unsigned int i; } c;
  c.i = ((unsigned int)u) << 16;
  return c.f;
}

__device__ __forceinline__ void gload_lds16(const void* g, void* l) {
  __builtin_amdgcn_global_load_lds((const __attribute__((address_space(1))) void*)g,
                                   (__attribute__((address_space(3))) void*)l,
                                   16, 0, 0);
}

// fast tanh: 1 - 2/(exp2(2x*log2e)+1); HW exp2+rcp, exact limits at +-inf
__device__ __forceinline__ float fast_tanh(float x) {
  float e = __builtin_amdgcn_exp2f(x * 2.885390082f);
  return 1.0f - 2.0f * __builtin_amdgcn_rcpf(e + 1.0f);
}

// ---------------- fused weight/input prep (one launch) ----------------
#define PREP_NBLK 20492

__global__ __launch_bounds__(256)
void prep_all(const float* __restrict__ x, unsigned short* __restrict__ x_bf,
              const float* __restrict__ Wq, const float* __restrict__ Wk,
              const float* __restrict__ Wv, unsigned short* __restrict__ Wqkvt,
              const float* __restrict__ Wo, unsigned short* __restrict__ Wot,
              const float* __restrict__ W1, unsigned short* __restrict__ W1t,
              const float* __restrict__ W2, unsigned short* __restrict__ W2t,
              const float* __restrict__ bq, const float* __restrict__ bk,
              const float* __restrict__ bv, float* __restrict__ bqkv)
{
  __shared__ float t[32][33];
  const int bid = blockIdx.x;
  const int tid = threadIdx.x;
  const int tx = tid & 31, ty = tid >> 5;

  if (bid < 8192) {
    int i = bid * 256 + tid;
    float4 v = ((const float4*)x)[i];
    ushort4 o;
    o.x = f2b(v.x); o.y = f2b(v.y); o.z = f2b(v.z); o.w = f2b(v.w);
    ((ushort4*)x_bf)[i] = o;
    return;
  }
  if (bid < 11264) {
    int idx = bid - 8192;           // z*64 + y*32 + xb : z<48, y<2, xb<32
    int z = idx >> 6, y = (idx >> 5) & 1, xb = idx & 31;
    int which = z / 16, h = z % 16;
    const float* src = (which == 0 ? Wq : which == 1 ? Wk : Wv) + (size_t)h * ND * NDK;
    float scale = (which == 0) ? QSCALE : 1.0f;
    unsigned short* d = Wqkvt + (size_t)(which * 1024 + h * 64) * ND;
    int k0 = xb * 32, n0 = y * 32;
    for (int r = ty; r < 32; r += 8)
      t[r][tx] = src[(size_t)(k0 + r) * NDK + n0 + tx];
    __syncthreads();
    for (int r = ty; r < 32; r += 8)
      d[(size_t)(n0 + r) * ND + k0 + tx] = f2b(t[tx][r] * scale);
    return;
  }
  const float* src; unsigned short* dst; int ldsrc, lddst, k0, n0;
  if (bid < 12288) {
    int idx = bid - 11264; src = Wo; dst = Wot; ldsrc = 1024; lddst = 1024;
    k0 = (idx & 31) * 32; n0 = (idx >> 5) * 32;
  } else if (bid < 16384) {
    int idx = bid - 12288; src = W1; dst = W1t; ldsrc = 4096; lddst = 1024;
    k0 = (idx & 31) * 32; n0 = (idx >> 5) * 32;
  } else if (bid < 20480) {
    int idx = bid - 16384; src = W2; dst = W2t; ldsrc = 1024; lddst = 4096;
    k0 = (idx >> 5) * 32; n0 = (idx & 31) * 32;
  } else {
    int i = (bid - 20480) * 256 + tid;
    if (i < 3072) {
      float v = (i < 1024) ? bq[i] * QSCALE : (i < 2048 ? bk[i - 1024] : bv[i - 2048]);
      bqkv[i] = v;
    }
    return;
  }
  for (int r = ty; r < 32; r += 8)
    t[r][tx] = src[(size_t)(k0 + r) * ldsrc + n0 + tx];
  __syncthreads();
  for (int r = ty; r < 32; r += 8)
    dst[(size_t)(n0 + r) * lddst + k0 + tx] = f2b(t[tx][r]);
}

// V transpose: qkv [8192][3072] (v at col 2048+h*64) -> vt [64 bh][64 d][2048 s]
__global__ __launch_bounds__(256)
void transpose_v(const unsigned short* __restrict__ qkv, unsigned short* __restrict__ vt) {
  __shared__ unsigned short t[32][33];
  int bh = blockIdx.z; int b = bh >> 4, h = bh & 15;
  int s0 = blockIdx.x * 32;
  int d0 = blockIdx.y * 32;
  int tx = threadIdx.x, ty = threadIdx.y;
  for (int r = ty; r < 32; r += 8)
    t[r][tx] = qkv[(size_t)(b * NS + s0 + r) * 3072 + 2048 + h * 64 + d0 + tx];
  __syncthreads();
  for (int r = ty; r < 32; r += 8)
    vt[((size_t)bh * 64 + d0 + r) * NS + s0 + tx] = t[tx][r];
}

// ---------------- GEMM 256x128 TRIPLE-buffered, counted vmcnt (T4) ----------------
// 8 waves (4M x 2N), BK=64, LDS 144KB (3 x (32+16)KB). Loop:
//   STAGE(buf[t+2]) ; COMPUTE(buf[t]) ; vmcnt(6) (tile t+1 landed, t+2 in flight) ;
//   raw s_barrier (NO vmcnt-0 drain -- that drain was the 2-phase latency wall).
// Race-free by construction: STAGE(t+2) writes the buffer whose last reader
// (COMPUTE(t-1)) finished two barriers ago. No asm lgkmcnt (compiler inserts its
// own ds_read waits; avoids the rule-18 hoist hazard). 8-granule XOR swizzle.
// EPI: 0 = bf16 store, 1 = f32 store, 2 = bf16 tanh store

template<int EPI>
__global__ __launch_bounds__(512, 1)
void gemm_bt(const unsigned short* __restrict__ A, const unsigned short* __restrict__ Bt,
             const float* __restrict__ bias, void* __restrict__ Cout,
             int M, int N, int K)
{
  __shared__ __align__(16) unsigned short As[3][256 * 64];   // 3 x 32 KB
  __shared__ __align__(16) unsigned short Bs[3][128 * 64];   // 3 x 16 KB

  const int nwg = gridDim.x;
  const int id = blockIdx.x;
  const int swz = (id & 7) * (nwg >> 3) + (id >> 3);
  const int nbx = N >> 7;
  const int mb = swz / nbx, nb = swz % nbx;
  const int m0 = mb * 256;
  const int n0 = nb * 128;

  const int tid = threadIdx.x;
  const int wave = tid >> 6, lane = tid & 63;
  const int l16 = lane & 15, lhi = lane >> 4;
  const int wr = wave >> 1, wc = wave & 1;   // 4M x 2N wave grid

  const int rowL = lane >> 3;
  const int gg = (lane & 7) ^ rowL;

  f32x4 acc[4][4] = {};

  // 6 gload_lds per thread per tile (4 A-chunks + 2 B-chunks)
  auto STAGE = [&](unsigned short* la, unsigned short* lb, int kt) {
    const int k0 = kt * 64;
#pragma unroll
    for (int c = wave * 4; c < wave * 4 + 4; ++c)
      gload_lds16(A + (size_t)(m0 + c * 8 + rowL) * K + (k0 + gg * 8), la + c * 512);
#pragma unroll
    for (int c = wave * 2; c < wave * 2 + 2; ++c)
      gload_lds16(Bt + (size_t)(n0 + c * 8 + rowL) * K + (k0 + gg * 8), lb + c * 512);
  };

  auto COMPUTE = [&](const char* as, const char* bs) {
    short8 af[4][2], bf[4][2];
#pragma unroll
    for (int i = 0; i < 4; ++i) {
      const int row = wr * 64 + i * 16 + l16;
      const char* rb = as + row * 128;
#pragma unroll
      for (int ks = 0; ks < 2; ++ks)
        af[i][ks] = *(const short8*)(rb + (((ks * 4 + lhi) ^ (row & 7)) << 4));
    }
#pragma unroll
    for (int j = 0; j < 4; ++j) {
      const int row = wc * 64 + j * 16 + l16;
      const char* rb = bs + row * 128;
#pragma unroll
      for (int ks = 0; ks < 2; ++ks)
        bf[j][ks] = *(const short8*)(rb + (((ks * 4 + lhi) ^ (row & 7)) << 4));
    }
    __builtin_amdgcn_s_setprio(1);
#pragma unroll
    for (int i = 0; i < 4; ++i)
#pragma unroll
      for (int j = 0; j < 4; ++j)
#pragma unroll
        for (int ks = 0; ks < 2; ++ks)
          acc[i][j] = __builtin_amdgcn_mfma_f32_16x16x32_bf16(af[i][ks], bf[j][ks],
                                                              acc[i][j], 0, 0, 0);
    __builtin_amdgcn_s_setprio(0);
  };

  unsigned short *a0 = &As[0][0], *a1 = &As[1][0], *a2 = &As[2][0];
  unsigned short *b0 = &Bs[0][0], *b1 = &Bs[1][0], *b2 = &Bs[2][0];

  const int NT = K >> 6;
  STAGE(a0, b0, 0);
  STAGE(a1, b1, 1);
  asm volatile("s_waitcnt vmcnt(6)" ::: "memory");   // tile 0 landed; tile 1 in flight
  asm volatile("s_barrier" ::: "memory");

  for (int t = 0; t < NT; ++t) {
    if (t + 2 < NT) STAGE(a2, b2, t + 2);
    COMPUTE((const char*)a0, (const char*)b0);
    if (t + 1 < NT) {
      if (t + 2 < NT) { asm volatile("s_waitcnt vmcnt(6)" ::: "memory"); }
      else            { asm volatile("s_waitcnt vmcnt(0)" ::: "memory"); }
      asm volatile("s_barrier" ::: "memory");
    }
    unsigned short* ta = a0; a0 = a1; a1 = a2; a2 = ta;
    unsigned short* tb = b0; b0 = b1; b1 = b2; b2 = tb;
  }

#pragma unroll
  for (int i = 0; i < 4; ++i) {
    const int row = m0 + wr * 64 + i * 16 + lhi * 4;
#pragma unroll
    for (int j = 0; j < 4; ++j) {
      const int col = n0 + wc * 64 + j * 16 + l16;
      const float bv = bias[col];
#pragma unroll
      for (int r = 0; r < 4; ++r) {
        float v = acc[i][j][r] + bv;
        size_t idx = (size_t)(row + r) * N + col;
        if (EPI == 0)      ((unsigned short*)Cout)[idx] = f2b(v);
        else if (EPI == 1) ((float*)Cout)[idx] = v;
        else               ((unsigned short*)Cout)[idx] = f2b(fast_tanh(v));
      }
    }
  }
}

// ---------------- flash attention (QBLK=256: 2 subtiles/wave) ----------------
// qkv: bf16 [8192][3072] (q pre-scaled to log2 domain); vtg: bf16 [64][64][2048]
// ctx: bf16 [8192][1024]. 512 blocks (XCD-swizzled), 8 waves x 32 q-rows (2x16).
// kf/vf LDS fragments shared across subtiles; P = exp2(S); row sums via P @ ones.

__global__ __launch_bounds__(512)
void attn_fwd(const unsigned short* __restrict__ qkv, const unsigned short* __restrict__ vtg,
              unsigned short* __restrict__ ctx)
{
  // bijective XCD swizzle: 512 blocks = 8 XCDs x 64
  const int id = blockIdx.x;
  const int swz = (id & 7) * 64 + (id >> 3);
  const int qt = swz & 7;                  // 8 q-tiles of 256 rows
  const int bh = swz >> 3;
  const int b = bh >> 4, h = bh & 15;
  const int row0 = b * NS + qt * 256;
  const int tid = threadIdx.x;
  const int wave = tid >> 6, lane = tid & 63;
  const int l16 = lane & 15, lhi = lane >> 4;

  __shared__ __align__(16) unsigned short Ks[2][64 * 64];    // 2 x 8 KB
  __shared__ __align__(16) unsigned short Vs[2][64 * 64];    // [d][key], swizzled
  __shared__ __align__(16) unsigned short Ps[16][16 * 64];   // per wave x sub, swizzled

  const unsigned short* kbase = qkv + ND + (size_t)h * 64;      // + row*3072
  const unsigned short* vbase = vtg + (size_t)bh * 64 * NS;     // + d*NS + key

  // staging: chunk c = tid in [0,512): row=c>>3, swizzled slot (c&7)*16B
  const int r0 = tid >> 3;
  const int f0 = ((tid & 7) ^ (r0 & 7)) * 8;
  const int ldsb0 = wave * 512;   // element base (chunk = wave*64 + lane)

  // loop-invariant swizzled LDS byte offsets
  const int lbase = l16 * 128;
  const int xs = (l16 & 7) << 4;
  const int kvo0 = (lhi * 16) ^ xs;
  const int kvo1 = (64 + lhi * 16) ^ xs;
  int pjo[4];
#pragma unroll
  for (int j = 0; j < 4; ++j)
    pjo[j] = (j * 32 + lhi * 8) ^ xs;

  // all-ones bf16 B-operand for the row-sum MFMA
  short8 ones8;
#pragma unroll
  for (int e = 0; e < 8; ++e) ones8[e] = (short)0x3F80;

  // Q fragments: 2 subtiles of 16 q-rows each
  short8 qf[2][2];
#pragma unroll
  for (int sub = 0; sub < 2; ++sub) {
    const unsigned short* qrow =
        qkv + (size_t)(row0 + wave * 32 + sub * 16 + l16) * 3072 + h * 64;
    qf[sub][0] = *(const short8*)(qrow + lhi * 8);
    qf[sub][1] = *(const short8*)(qrow + 32 + lhi * 8);
  }

  f32x4 o[2][4] = {};
  f32x4 o5[2] = {};   // row sums per subtile

  auto STAGE = [&](int buf, int kt) {
    const size_t kr = (size_t)(b * NS + kt * 64);
    const int kb64 = kt * 64;
    gload_lds16(kbase + (kr + r0) * 3072 + f0, &Ks[buf][ldsb0]);
    gload_lds16(vbase + (size_t)r0 * NS + kb64 + f0, &Vs[buf][ldsb0]);
  };

  auto COMPUTE = [&](int buf) {
    const char* kb = (const char*)&Ks[buf][0];
    const char* vb = (const char*)&Vs[buf][0];
    char* pb0 = (char*)&Ps[wave * 2 + 0][0];
    char* pb1 = (char*)&Ps[wave * 2 + 1][0];

    // S^T = K @ Q^T for both subtiles; kf shared
    f32x4 s[2][4] = {};
    __builtin_amdgcn_s_setprio(1);
#pragma unroll
    for (int c = 0; c < 2; ++c) {
      const int kvo = c ? kvo1 : kvo0;
#pragma unroll
      for (int j = 0; j < 4; ++j) {
        short8 kf = *(const short8*)(kb + lbase + j * 2048 + kvo);
        s[0][j] = __builtin_amdgcn_mfma_f32_16x16x32_bf16(kf, qf[0][c], s[0][j], 0, 0, 0);
        s[1][j] = __builtin_amdgcn_mfma_f32_16x16x32_bf16(kf, qf[1][c], s[1][j], 0, 0, 0);
      }
    }
    __builtin_amdgcn_s_setprio(0);

    // P = exp2(S); one b64 write per (sub, j)
#pragma unroll
    for (int sub = 0; sub < 2; ++sub) {
      char* pb = sub ? pb1 : pb0;
#pragma unroll
      for (int j = 0; j < 4; ++j) {
#pragma unroll
        for (int r = 0; r < 4; ++r)
          s[sub][j][r] = __builtin_amdgcn_exp2f(s[sub][j][r]);
        unsigned int lo = (unsigned int)f2b(s[sub][j][0]) | ((unsigned int)f2b(s[sub][j][1]) << 16);
        unsigned int hi = (unsigned int)f2b(s[sub][j][2]) | ((unsigned int)f2b(s[sub][j][3]) << 16);
        unsigned long long w = (unsigned long long)lo | ((unsigned long long)hi << 32);
        *(unsigned long long*)(pb + lbase + pjo[j]) = w;
      }
    }

    // O += P @ V (vf shared); row-sum += P @ ones
    __builtin_amdgcn_s_setprio(1);
#pragma unroll
    for (int c = 0; c < 2; ++c) {
      const int kvo = c ? kvo1 : kvo0;
      short8 pf0 = *(const short8*)(pb0 + lbase + kvo);
      short8 pf1 = *(const short8*)(pb1 + lbase + kvo);
#pragma unroll
      for (int j = 0; j < 4; ++j) {
        short8 vf = *(const short8*)(vb + lbase + j * 2048 + kvo);
        o[0][j] = __builtin_amdgcn_mfma_f32_16x16x32_bf16(pf0, vf, o[0][j], 0, 0, 0);
        o[1][j] = __builtin_amdgcn_mfma_f32_16x16x32_bf16(pf1, vf, o[1][j], 0, 0, 0);
      }
      o5[0] = __builtin_amdgcn_mfma_f32_16x16x32_bf16(pf0, ones8, o5[0], 0, 0, 0);
      o5[1] = __builtin_amdgcn_mfma_f32_16x16x32_bf16(pf1, ones8, o5[1], 0, 0, 0);
    }
    __builtin_amdgcn_s_setprio(0);
  };

  STAGE(0, 0);
  __syncthreads();
  for (int kt = 0; kt < NS / 64; kt += 2) {
    STAGE(1, kt + 1);
    COMPUTE(0);
    __syncthreads();
    if (kt + 2 < NS / 64) STAGE(0, kt + 2);
    COMPUTE(1);
    __syncthreads();
  }

  // normalize: o5[sub][r] = sum_k P[q][k] for q = wave*32 + sub*16 + lhi*4 + r
#pragma unroll
  for (int sub = 0; sub < 2; ++sub) {
    float rinv[4];
#pragma unroll
    for (int r = 0; r < 4; ++r) rinv[r] = 1.0f / o5[sub][r];
#pragma unroll
    for (int j = 0; j < 4; ++j)
#pragma unroll
      for (int r = 0; r < 4; ++r) {
        const int row = row0 + wave * 32 + sub * 16 + lhi * 4 + r;
        ctx[(size_t)row * ND + h * 64 + j * 16 + l16] = f2b(o[sub][j][r] * rinv[r]);
      }
  }
}

// ---------------- fused residual + LayerNorm (bf16 inputs) ----------------
// OUTF32 = 0: out bf16 (h = LN(x + attn_out)); 1: out f32 (final output)

template<int OUTF32>
__global__ __launch_bounds__(256)
void ln_fused(const unsigned short* __restrict__ xa, const unsigned short* __restrict__ xb,
              const float* __restrict__ g, const float* __restrict__ beta, void* out_)
{
  const int row = blockIdx.x;
  const int tid = threadIdx.x;
  const int wave = tid >> 6, lane = tid & 63;
  __shared__ float r1[4], r2[4];

  ushort4 au = ((const ushort4*)(xa + (size_t)row * ND))[tid];
  ushort4 bu = ((const ushort4*)(xb + (size_t)row * ND))[tid];
  float v0 = b2f(au.x) + b2f(bu.x), v1 = b2f(au.y) + b2f(bu.y);
  float v2 = b2f(au.z) + b2f(bu.z), v3 = b2f(au.w) + b2f(bu.w);

  float sm = v0 + v1 + v2 + v3;
#pragma unroll
  for (int d = 1; d < 64; d <<= 1) sm += __shfl_xor(sm, d);
  if (lane == 0) r1[wave] = sm;
  __syncthreads();
  const float mu = (r1[0] + r1[1] + r1[2] + r1[3]) * (1.0f / ND);
  const float d0 = v0 - mu, d1 = v1 - mu, d2 = v2 - mu, d3 = v3 - mu;
  float vs = d0 * d0 + d1 * d1 + d2 * d2 + d3 * d3;
#pragma unroll
  for (int d = 1; d < 64; d <<= 1) vs += __shfl_xor(vs, d);
  if (lane == 0) r2[wave] = vs;
  __syncthreads();
  const float var = (r2[0] + r2[1] + r2[2] + r2[3]) * (1.0f / ND);
  const float inv = rsqrtf(var + 1e-5f);
  float4 gg = ((const float4*)g)[tid];
  float4 bb = ((const float4*)beta)[tid];
  float o0 = d0 * inv * gg.x + bb.x;
  float o1 = d1 * inv * gg.y + bb.y;
  float o2 = d2 * inv * gg.z + bb.z;
  float o3 = d3 * inv * gg.w + bb.w;
  if (OUTF32 == 0) {
    ushort4 w; w.x = f2b(o0); w.y = f2b(o1); w.z = f2b(o2); w.w = f2b(o3);
    ((ushort4*)((unsigned short*)out_ + (size_t)row * ND))[tid] = w;
  } else {
    float4 ov; ov.x = o0; ov.y = o1; ov.z = o2; ov.w = o3;
    ((float4*)((float*)out_ + (size_t)row * ND))[tid] = ov;
  }
}

// ---------------- launch ----------------

extern "C" void kernel_launch(void* const* d_in, const int* in_sizes, int n_in,
                              void* d_out, int out_size, void* d_ws, size_t ws_size,
                              hipStream_t stream)
{
  (void)in_sizes; (void)n_in; (void)out_size; (void)ws_size;
  const float* x   = (const float*)d_in[0];
  const float* Wq  = (const float*)d_in[1];
  const float* bq  = (const float*)d_in[2];
  const float* Wk  = (const float*)d_in[3];
  const float* bk  = (const float*)d_in[4];
  const float* Wv  = (const float*)d_in[5];
  const float* bv  = (const float*)d_in[6];
  const float* Wo  = (const float*)d_in[7];
  const float* bo  = (const float*)d_in[8];
  const float* g1  = (const float*)d_in[9];
  const float* be1 = (const float*)d_in[10];
  const float* W1  = (const float*)d_in[11];
  const float* b1  = (const float*)d_in[12];
  const float* W2  = (const float*)d_in[13];
  const float* b2  = (const float*)d_in[14];
  const float* g2  = (const float*)d_in[15];
  const float* be2 = (const float*)d_in[16];

  char* ws = (char*)d_ws;
  const size_t MB = 1ull << 20;
  unsigned short* x_bf  = (unsigned short*)(ws);             // 16 MiB, alive until LN1
  unsigned short* qkv   = (unsigned short*)(ws + 16 * MB);   // 48 MiB, dead after attn
  unsigned short* aout  = (unsigned short*)(ws + 16 * MB);   // 16 MiB bf16, overlays qkv (after attn)
  unsigned short* ff1   = (unsigned short*)(ws);             // 64 MiB, overlays x_bf+qkv (after LN1)
  unsigned short* ctx   = (unsigned short*)(ws + 64 * MB);   // 16 MiB, dead after out-proj
  unsigned short* h_bf  = (unsigned short*)(ws + 64 * MB);   // 16 MiB, overlays ctx
  unsigned short* Wqkvt = (unsigned short*)(ws + 80 * MB);   // 6 MiB
  unsigned short* Wot   = (unsigned short*)(ws + 86 * MB);   // 2 MiB
  unsigned short* W1t   = (unsigned short*)(ws + 88 * MB);   // 8 MiB
  unsigned short* W2t   = (unsigned short*)(ws + 96 * MB);   // 8 MiB
  float*          bqkv  = (float*)(ws + 104 * MB);           // 12 KiB
  unsigned short* ffout = (unsigned short*)(ws + 105 * MB);  // 16 MiB bf16
  unsigned short* vtg   = (unsigned short*)(ws + 121 * MB);  // 16 MiB (keeps x_bf alive)

  // fused prep: cvt + all weight transposes + bias pack (one launch)
  prep_all<<<PREP_NBLK, 256, 0, stream>>>(x, x_bf, Wq, Wk, Wv, Wqkvt,
                                          Wo, Wot, W1, W1t, W2, W2t,
                                          bq, bk, bv, bqkv);

  // QKV projection (q pre-scaled into log2 domain): 768 blocks (3 exact CU-waves)
  gemm_bt<0><<<(NM / 256) * (3072 / 128), 512, 0, stream>>>(x_bf, Wqkvt, bqkv, qkv, NM, 3072, 1024);
  // V transpose
  transpose_v<<<dim3(64, 2, 64), dim3(32, 8), 0, stream>>>(qkv, vtg);
  // attention (QBLK=256, 8 waves x 2 subtiles)
  attn_fwd<<<512, 512, 0, stream>>>(qkv, vtg, ctx);
  // output projection -> bf16: 256 blocks (1 exact CU-wave)
  gemm_bt<0><<<(NM / 256) * (1024 / 128), 512, 0, stream>>>(ctx, Wot, bo, aout, NM, 1024, 1024);
  // h = LN(x + attn_out) -> bf16 (ctx dead; h_bf overlays it)
  ln_fused<0><<<NM, 256, 0, stream>>>(x_bf, aout, g1, be1, h_bf);
  // FFN1 with tanh: 256x128 tile, 1024 blocks (4 exact CU-waves)
  gemm_bt<2><<<(NM / 256) * (4096 / 128), 512, 0, stream>>>(h_bf, W1t, b1, ff1, NM, 4096, 1024);
  // FFN2 -> bf16: 256 blocks (1 exact CU-wave)
  gemm_bt<0><<<(NM / 256) * (1024 / 128), 512, 0, stream>>>(ff1, W2t, b2, ffout, NM, 1024, 4096);
  // out = LN(h + ff) -> f32
  ln_fused<1><<<NM, 256, 0, stream>>>(h_bf, ffout, g2, be2, (float*)d_out);
}

// Round 19
// 398.787 us; speedup vs baseline: 1.0827x; 1.0827x over previous
//
#include <hip/hip_runtime.h>
#include <hip/hip_bf16.h>
#include <math.h>

typedef __attribute__((ext_vector_type(8))) short short8;
typedef __attribute__((ext_vector_type(4))) float f32x4;

#define NB 4
#define NS 2048
#define ND 1024
#define NH 16
#define NDK 64
#define NF 4096
#define NM (NB*NS)   // 8192 rows total

// 1/sqrt(DK) * log2(e): scores come out of QK^T already in log2 domain
#define QSCALE 0.18033688f

__device__ __forceinline__ unsigned short f2b(float f) {
  union { __hip_bfloat16 h; unsigned short u; } c;
  c.h = __float2bfloat16(f);
  return c.u;
}

__device__ __forceinline__ float b2f(unsigned short u) {
  union { float f; unsigned int i; } c;
  c.i = ((unsigned int)u) << 16;
  return c.f;
}

__device__ __forceinline__ void gload_lds16(const void* g, void* l) {
  __builtin_amdgcn_global_load_lds((const __attribute__((address_space(1))) void*)g,
                                   (__attribute__((address_space(3))) void*)l,
                                   16, 0, 0);
}

// fast tanh: 1 - 2/(exp2(2x*log2e)+1); HW exp2+rcp, exact limits at +-inf
__device__ __forceinline__ float fast_tanh(float x) {
  float e = __builtin_amdgcn_exp2f(x * 2.885390082f);
  return 1.0f - 2.0f * __builtin_amdgcn_rcpf(e + 1.0f);
}

// ---------------- fused weight/input prep (one launch) ----------------
#define PREP_NBLK 20492

__global__ __launch_bounds__(256)
void prep_all(const float* __restrict__ x, unsigned short* __restrict__ x_bf,
              const float* __restrict__ Wq, const float* __restrict__ Wk,
              const float* __restrict__ Wv, unsigned short* __restrict__ Wqkvt,
              const float* __restrict__ Wo, unsigned short* __restrict__ Wot,
              const float* __restrict__ W1, unsigned short* __restrict__ W1t,
              const float* __restrict__ W2, unsigned short* __restrict__ W2t,
              const float* __restrict__ bq, const float* __restrict__ bk,
              const float* __restrict__ bv, float* __restrict__ bqkv)
{
  __shared__ float t[32][33];
  const int bid = blockIdx.x;
  const int tid = threadIdx.x;
  const int tx = tid & 31, ty = tid >> 5;

  if (bid < 8192) {
    int i = bid * 256 + tid;
    float4 v = ((const float4*)x)[i];
    ushort4 o;
    o.x = f2b(v.x); o.y = f2b(v.y); o.z = f2b(v.z); o.w = f2b(v.w);
    ((ushort4*)x_bf)[i] = o;
    return;
  }
  if (bid < 11264) {
    int idx = bid - 8192;           // z*64 + y*32 + xb : z<48, y<2, xb<32
    int z = idx >> 6, y = (idx >> 5) & 1, xb = idx & 31;
    int which = z / 16, h = z % 16;
    const float* src = (which == 0 ? Wq : which == 1 ? Wk : Wv) + (size_t)h * ND * NDK;
    float scale = (which == 0) ? QSCALE : 1.0f;
    unsigned short* d = Wqkvt + (size_t)(which * 1024 + h * 64) * ND;
    int k0 = xb * 32, n0 = y * 32;
    for (int r = ty; r < 32; r += 8)
      t[r][tx] = src[(size_t)(k0 + r) * NDK + n0 + tx];
    __syncthreads();
    for (int r = ty; r < 32; r += 8)
      d[(size_t)(n0 + r) * ND + k0 + tx] = f2b(t[tx][r] * scale);
    return;
  }
  const float* src; unsigned short* dst; int ldsrc, lddst, k0, n0;
  if (bid < 12288) {
    int idx = bid - 11264; src = Wo; dst = Wot; ldsrc = 1024; lddst = 1024;
    k0 = (idx & 31) * 32; n0 = (idx >> 5) * 32;
  } else if (bid < 16384) {
    int idx = bid - 12288; src = W1; dst = W1t; ldsrc = 4096; lddst = 1024;
    k0 = (idx & 31) * 32; n0 = (idx >> 5) * 32;
  } else if (bid < 20480) {
    int idx = bid - 16384; src = W2; dst = W2t; ldsrc = 1024; lddst = 4096;
    k0 = (idx >> 5) * 32; n0 = (idx & 31) * 32;
  } else {
    int i = (bid - 20480) * 256 + tid;
    if (i < 3072) {
      float v = (i < 1024) ? bq[i] * QSCALE : (i < 2048 ? bk[i - 1024] : bv[i - 2048]);
      bqkv[i] = v;
    }
    return;
  }
  for (int r = ty; r < 32; r += 8)
    t[r][tx] = src[(size_t)(k0 + r) * ldsrc + n0 + tx];
  __syncthreads();
  for (int r = ty; r < 32; r += 8)
    dst[(size_t)(n0 + r) * lddst + k0 + tx] = f2b(t[tx][r]);
}

// V transpose: qkv [8192][3072] (v at col 2048+h*64) -> vt [64 bh][64 d][2048 s]
__global__ __launch_bounds__(256)
void transpose_v(const unsigned short* __restrict__ qkv, unsigned short* __restrict__ vt) {
  __shared__ unsigned short t[32][33];
  int bh = blockIdx.z; int b = bh >> 4, h = bh & 15;
  int s0 = blockIdx.x * 32;
  int d0 = blockIdx.y * 32;
  int tx = threadIdx.x, ty = threadIdx.y;
  for (int r = ty; r < 32; r += 8)
    t[r][tx] = qkv[(size_t)(b * NS + s0 + r) * 3072 + 2048 + h * 64 + d0 + tx];
  __syncthreads();
  for (int r = ty; r < 32; r += 8)
    vt[((size_t)bh * 64 + d0 + r) * NS + s0 + tx] = t[tx][r];
}

// ---------------- GEMM 256x128: C = A @ Bt^T + bias ----------------
// 8 waves (4M x 2N), BK=64, double-buffered 96KB LDS, 2-phase loop (1 barrier/tile),
// unrolled x2, 8-granule XOR swizzle. Used for QKV / out-proj / FFN2.
// EPI: 0 = bf16 store, 1 = f32 store, 2 = bf16 tanh store

template<int EPI>
__global__ __launch_bounds__(512, 1)
void gemm_bt(const unsigned short* __restrict__ A, const unsigned short* __restrict__ Bt,
             const float* __restrict__ bias, void* __restrict__ Cout,
             int M, int N, int K)
{
  __shared__ __align__(16) unsigned short As[2][256 * 64];   // 2 x 32 KB
  __shared__ __align__(16) unsigned short Bs[2][128 * 64];   // 2 x 16 KB

  const int nwg = gridDim.x;
  const int id = blockIdx.x;
  const int swz = (id & 7) * (nwg >> 3) + (id >> 3);
  const int nbx = N >> 7;
  const int mb = swz / nbx, nb = swz % nbx;
  const int m0 = mb * 256;
  const int n0 = nb * 128;

  const int tid = threadIdx.x;
  const int wave = tid >> 6, lane = tid & 63;
  const int l16 = lane & 15, lhi = lane >> 4;
  const int wr = wave >> 1, wc = wave & 1;   // 4M x 2N wave grid

  const int rowL = lane >> 3;
  const int gg = (lane & 7) ^ rowL;

  f32x4 acc[4][4] = {};

  auto STAGE = [&](int buf, int kt) {
    const int k0 = kt * 64;
#pragma unroll
    for (int c = wave * 4; c < wave * 4 + 4; ++c)
      gload_lds16(A + (size_t)(m0 + c * 8 + rowL) * K + (k0 + gg * 8), &As[buf][c * 512]);
#pragma unroll
    for (int c = wave * 2; c < wave * 2 + 2; ++c)
      gload_lds16(Bt + (size_t)(n0 + c * 8 + rowL) * K + (k0 + gg * 8), &Bs[buf][c * 512]);
  };

  auto COMPUTE = [&](int buf) {
    const char* as = (const char*)&As[buf][0];
    const char* bs = (const char*)&Bs[buf][0];
    short8 af[4][2], bf[4][2];
#pragma unroll
    for (int i = 0; i < 4; ++i) {
      const int row = wr * 64 + i * 16 + l16;
      const char* rb = as + row * 128;
#pragma unroll
      for (int ks = 0; ks < 2; ++ks)
        af[i][ks] = *(const short8*)(rb + (((ks * 4 + lhi) ^ (row & 7)) << 4));
    }
#pragma unroll
    for (int j = 0; j < 4; ++j) {
      const int row = wc * 64 + j * 16 + l16;
      const char* rb = bs + row * 128;
#pragma unroll
      for (int ks = 0; ks < 2; ++ks)
        bf[j][ks] = *(const short8*)(rb + (((ks * 4 + lhi) ^ (row & 7)) << 4));
    }
    __builtin_amdgcn_s_setprio(1);
#pragma unroll
    for (int i = 0; i < 4; ++i)
#pragma unroll
      for (int j = 0; j < 4; ++j)
#pragma unroll
        for (int ks = 0; ks < 2; ++ks)
          acc[i][j] = __builtin_amdgcn_mfma_f32_16x16x32_bf16(af[i][ks], bf[j][ks],
                                                              acc[i][j], 0, 0, 0);
    __builtin_amdgcn_s_setprio(0);
  };

  const int NT = K >> 6;   // 16 or 64: always even
  STAGE(0, 0);
  __syncthreads();
  for (int j = 0; j < NT; j += 2) {
    STAGE(1, j + 1);
    COMPUTE(0);
    __syncthreads();
    if (j + 2 < NT) STAGE(0, j + 2);
    COMPUTE(1);
    __syncthreads();
  }

#pragma unroll
  for (int i = 0; i < 4; ++i) {
    const int row = m0 + wr * 64 + i * 16 + lhi * 4;
#pragma unroll
    for (int j = 0; j < 4; ++j) {
      const int col = n0 + wc * 64 + j * 16 + l16;
      const float bv = bias[col];
#pragma unroll
      for (int r = 0; r < 4; ++r) {
        float v = acc[i][j][r] + bv;
        size_t idx = (size_t)(row + r) * N + col;
        if (EPI == 0)      ((unsigned short*)Cout)[idx] = f2b(v);
        else if (EPI == 1) ((float*)Cout)[idx] = v;
        else               ((unsigned short*)Cout)[idx] = f2b(fast_tanh(v));
      }
    }
  }
}

// ---------------- GEMM 256x256 (FFN1): BK=64 (verified best) ----------------
// 2-phase/1-barrier skeleton, 8 waves as 2M x 4N, acc[8][4]:
// 64 MFMA per 24 ds_reads per wave per K-tile. LDS 128KB dbuf, conflict-free
// 8-granule XOR swizzle on 128B rows. setprio hoisted around the whole MFMA block.

template<int EPI>
__global__ __launch_bounds__(512, 2)
void gemm256(const unsigned short* __restrict__ A, const unsigned short* __restrict__ Bt,
             const float* __restrict__ bias, void* __restrict__ Cout,
             int M, int N, int K)
{
  __shared__ __align__(16) unsigned short As[2][256 * 64];   // 2 x 32 KB
  __shared__ __align__(16) unsigned short Bs[2][256 * 64];   // 2 x 32 KB

  const int nwg = gridDim.x;
  const int id = blockIdx.x;
  const int swz = (id & 7) * (nwg >> 3) + (id >> 3);
  const int nbx = N >> 8;
  const int mb = swz / nbx, nb = swz % nbx;
  const int m0 = mb * 256;
  const int n0 = nb * 256;

  const int tid = threadIdx.x;
  const int wave = tid >> 6, lane = tid & 63;
  const int l16 = lane & 15, lhi = lane >> 4;
  const int wr = wave >> 2, wc = wave & 3;   // 2M x 4N wave grid

  const int rowL = lane >> 3;
  const int gg = (lane & 7) ^ rowL;

  f32x4 acc[8][4] = {};

  auto STAGE = [&](int buf, int kt) {
    const int k0 = kt * 64;
#pragma unroll
    for (int c = wave * 4; c < wave * 4 + 4; ++c) {
      gload_lds16(A + (size_t)(m0 + c * 8 + rowL) * K + (k0 + gg * 8), &As[buf][c * 512]);
      gload_lds16(Bt + (size_t)(n0 + c * 8 + rowL) * K + (k0 + gg * 8), &Bs[buf][c * 512]);
    }
  };

  auto COMPUTE = [&](int buf) {
    const char* as = (const char*)&As[buf][0];
    const char* bs = (const char*)&Bs[buf][0];
    short8 bf[4][2];
#pragma unroll
    for (int j = 0; j < 4; ++j) {
      const int row = wc * 64 + j * 16 + l16;
      const char* rb = bs + row * 128;
#pragma unroll
      for (int ks = 0; ks < 2; ++ks)
        bf[j][ks] = *(const short8*)(rb + (((ks * 4 + lhi) ^ (row & 7)) << 4));
    }
    __builtin_amdgcn_s_setprio(1);
#pragma unroll
    for (int i = 0; i < 8; ++i) {
      const int row = wr * 128 + i * 16 + l16;
      const char* rb = as + row * 128;
      short8 af[2];
#pragma unroll
      for (int ks = 0; ks < 2; ++ks)
        af[ks] = *(const short8*)(rb + (((ks * 4 + lhi) ^ (row & 7)) << 4));
#pragma unroll
      for (int j = 0; j < 4; ++j)
#pragma unroll
        for (int ks = 0; ks < 2; ++ks)
          acc[i][j] = __builtin_amdgcn_mfma_f32_16x16x32_bf16(af[ks], bf[j][ks],
                                                              acc[i][j], 0, 0, 0);
    }
    __builtin_amdgcn_s_setprio(0);
  };

  const int NT = K >> 6;
  STAGE(0, 0);
  __syncthreads();
  for (int j = 0; j < NT; j += 2) {
    STAGE(1, j + 1);
    COMPUTE(0);
    __syncthreads();
    if (j + 2 < NT) STAGE(0, j + 2);
    COMPUTE(1);
    __syncthreads();
  }

#pragma unroll
  for (int i = 0; i < 8; ++i) {
    const int row = m0 + wr * 128 + i * 16 + lhi * 4;
#pragma unroll
    for (int j = 0; j < 4; ++j) {
      const int col = n0 + wc * 64 + j * 16 + l16;
      const float bv = bias[col];
#pragma unroll
      for (int r = 0; r < 4; ++r) {
        float v = acc[i][j][r] + bv;
        size_t idx = (size_t)(row + r) * N + col;
        if (EPI == 0)      ((unsigned short*)Cout)[idx] = f2b(v);
        else if (EPI == 1) ((float*)Cout)[idx] = v;
        else               ((unsigned short*)Cout)[idx] = f2b(fast_tanh(v));
      }
    }
  }
}

// ---------------- flash attention (QBLK=256: 2 subtiles/wave) ----------------
// qkv: bf16 [8192][3072] (q pre-scaled to log2 domain); vtg: bf16 [64][64][2048]
// ctx: bf16 [8192][1024]. 512 blocks (XCD-swizzled), 8 waves x 32 q-rows (2x16).
// kf/vf LDS fragments shared across subtiles; P = exp2(S); row sums via P @ ones.

__global__ __launch_bounds__(512)
void attn_fwd(const unsigned short* __restrict__ qkv, const unsigned short* __restrict__ vtg,
              unsigned short* __restrict__ ctx)
{
  // bijective XCD swizzle: 512 blocks = 8 XCDs x 64
  const int id = blockIdx.x;
  const int swz = (id & 7) * 64 + (id >> 3);
  const int qt = swz & 7;                  // 8 q-tiles of 256 rows
  const int bh = swz >> 3;
  const int b = bh >> 4, h = bh & 15;
  const int row0 = b * NS + qt * 256;
  const int tid = threadIdx.x;
  const int wave = tid >> 6, lane = tid & 63;
  const int l16 = lane & 15, lhi = lane >> 4;

  __shared__ __align__(16) unsigned short Ks[2][64 * 64];    // 2 x 8 KB
  __shared__ __align__(16) unsigned short Vs[2][64 * 64];    // [d][key], swizzled
  __shared__ __align__(16) unsigned short Ps[16][16 * 64];   // per wave x sub, swizzled

  const unsigned short* kbase = qkv + ND + (size_t)h * 64;      // + row*3072
  const unsigned short* vbase = vtg + (size_t)bh * 64 * NS;     // + d*NS + key

  // staging: chunk c = tid in [0,512): row=c>>3, swizzled slot (c&7)*16B
  const int r0 = tid >> 3;
  const int f0 = ((tid & 7) ^ (r0 & 7)) * 8;
  const int ldsb0 = wave * 512;   // element base (chunk = wave*64 + lane)

  // loop-invariant swizzled LDS byte offsets
  const int lbase = l16 * 128;
  const int xs = (l16 & 7) << 4;
  const int kvo0 = (lhi * 16) ^ xs;
  const int kvo1 = (64 + lhi * 16) ^ xs;
  int pjo[4];
#pragma unroll
  for (int j = 0; j < 4; ++j)
    pjo[j] = (j * 32 + lhi * 8) ^ xs;

  // all-ones bf16 B-operand for the row-sum MFMA
  short8 ones8;
#pragma unroll
  for (int e = 0; e < 8; ++e) ones8[e] = (short)0x3F80;

  // Q fragments: 2 subtiles of 16 q-rows each
  short8 qf[2][2];
#pragma unroll
  for (int sub = 0; sub < 2; ++sub) {
    const unsigned short* qrow =
        qkv + (size_t)(row0 + wave * 32 + sub * 16 + l16) * 3072 + h * 64;
    qf[sub][0] = *(const short8*)(qrow + lhi * 8);
    qf[sub][1] = *(const short8*)(qrow + 32 + lhi * 8);
  }

  f32x4 o[2][4] = {};
  f32x4 o5[2] = {};   // row sums per subtile

  auto STAGE = [&](int buf, int kt) {
    const size_t kr = (size_t)(b * NS + kt * 64);
    const int kb64 = kt * 64;
    gload_lds16(kbase + (kr + r0) * 3072 + f0, &Ks[buf][ldsb0]);
    gload_lds16(vbase + (size_t)r0 * NS + kb64 + f0, &Vs[buf][ldsb0]);
  };

  auto COMPUTE = [&](int buf) {
    const char* kb = (const char*)&Ks[buf][0];
    const char* vb = (const char*)&Vs[buf][0];
    char* pb0 = (char*)&Ps[wave * 2 + 0][0];
    char* pb1 = (char*)&Ps[wave * 2 + 1][0];

    // S^T = K @ Q^T for both subtiles; kf shared
    f32x4 s[2][4] = {};
    __builtin_amdgcn_s_setprio(1);
#pragma unroll
    for (int c = 0; c < 2; ++c) {
      const int kvo = c ? kvo1 : kvo0;
#pragma unroll
      for (int j = 0; j < 4; ++j) {
        short8 kf = *(const short8*)(kb + lbase + j * 2048 + kvo);
        s[0][j] = __builtin_amdgcn_mfma_f32_16x16x32_bf16(kf, qf[0][c], s[0][j], 0, 0, 0);
        s[1][j] = __builtin_amdgcn_mfma_f32_16x16x32_bf16(kf, qf[1][c], s[1][j], 0, 0, 0);
      }
    }
    __builtin_amdgcn_s_setprio(0);

    // P = exp2(S); one b64 write per (sub, j)
#pragma unroll
    for (int sub = 0; sub < 2; ++sub) {
      char* pb = sub ? pb1 : pb0;
#pragma unroll
      for (int j = 0; j < 4; ++j) {
#pragma unroll
        for (int r = 0; r < 4; ++r)
          s[sub][j][r] = __builtin_amdgcn_exp2f(s[sub][j][r]);
        unsigned int lo = (unsigned int)f2b(s[sub][j][0]) | ((unsigned int)f2b(s[sub][j][1]) << 16);
        unsigned int hi = (unsigned int)f2b(s[sub][j][2]) | ((unsigned int)f2b(s[sub][j][3]) << 16);
        unsigned long long w = (unsigned long long)lo | ((unsigned long long)hi << 32);
        *(unsigned long long*)(pb + lbase + pjo[j]) = w;
      }
    }

    // O += P @ V (vf shared); row-sum += P @ ones
    __builtin_amdgcn_s_setprio(1);
#pragma unroll
    for (int c = 0; c < 2; ++c) {
      const int kvo = c ? kvo1 : kvo0;
      short8 pf0 = *(const short8*)(pb0 + lbase + kvo);
      short8 pf1 = *(const short8*)(pb1 + lbase + kvo);
#pragma unroll
      for (int j = 0; j < 4; ++j) {
        short8 vf = *(const short8*)(vb + lbase + j * 2048 + kvo);
        o[0][j] = __builtin_amdgcn_mfma_f32_16x16x32_bf16(pf0, vf, o[0][j], 0, 0, 0);
        o[1][j] = __builtin_amdgcn_mfma_f32_16x16x32_bf16(pf1, vf, o[1][j], 0, 0, 0);
      }
      o5[0] = __builtin_amdgcn_mfma_f32_16x16x32_bf16(pf0, ones8, o5[0], 0, 0, 0);
      o5[1] = __builtin_amdgcn_mfma_f32_16x16x32_bf16(pf1, ones8, o5[1], 0, 0, 0);
    }
    __builtin_amdgcn_s_setprio(0);
  };

  STAGE(0, 0);
  __syncthreads();
  for (int kt = 0; kt < NS / 64; kt += 2) {
    STAGE(1, kt + 1);
    COMPUTE(0);
    __syncthreads();
    if (kt + 2 < NS / 64) STAGE(0, kt + 2);
    COMPUTE(1);
    __syncthreads();
  }

  // normalize: o5[sub][r] = sum_k P[q][k] for q = wave*32 + sub*16 + lhi*4 + r
#pragma unroll
  for (int sub = 0; sub < 2; ++sub) {
    float rinv[4];
#pragma unroll
    for (int r = 0; r < 4; ++r) rinv[r] = 1.0f / o5[sub][r];
#pragma unroll
    for (int j = 0; j < 4; ++j)
#pragma unroll
      for (int r = 0; r < 4; ++r) {
        const int row = row0 + wave * 32 + sub * 16 + lhi * 4 + r;
        ctx[(size_t)row * ND + h * 64 + j * 16 + l16] = f2b(o[sub][j][r] * rinv[r]);
      }
  }
}

// ---------------- fused residual + LayerNorm (bf16 inputs) ----------------
// OUTF32 = 0: out bf16 (h = LN(x + attn_out)); 1: out f32 (final output)

template<int OUTF32>
__global__ __launch_bounds__(256)
void ln_fused(const unsigned short* __restrict__ xa, const unsigned short* __restrict__ xb,
              const float* __restrict__ g, const float* __restrict__ beta, void* out_)
{
  const int row = blockIdx.x;
  const int tid = threadIdx.x;
  const int wave = tid >> 6, lane = tid & 63;
  __shared__ float r1[4], r2[4];

  ushort4 au = ((const ushort4*)(xa + (size_t)row * ND))[tid];
  ushort4 bu = ((const ushort4*)(xb + (size_t)row * ND))[tid];
  float v0 = b2f(au.x) + b2f(bu.x), v1 = b2f(au.y) + b2f(bu.y);
  float v2 = b2f(au.z) + b2f(bu.z), v3 = b2f(au.w) + b2f(bu.w);

  float sm = v0 + v1 + v2 + v3;
#pragma unroll
  for (int d = 1; d < 64; d <<= 1) sm += __shfl_xor(sm, d);
  if (lane == 0) r1[wave] = sm;
  __syncthreads();
  const float mu = (r1[0] + r1[1] + r1[2] + r1[3]) * (1.0f / ND);
  const float d0 = v0 - mu, d1 = v1 - mu, d2 = v2 - mu, d3 = v3 - mu;
  float vs = d0 * d0 + d1 * d1 + d2 * d2 + d3 * d3;
#pragma unroll
  for (int d = 1; d < 64; d <<= 1) vs += __shfl_xor(vs, d);
  if (lane == 0) r2[wave] = vs;
  __syncthreads();
  const float var = (r2[0] + r2[1] + r2[2] + r2[3]) * (1.0f / ND);
  const float inv = rsqrtf(var + 1e-5f);
  float4 gg = ((const float4*)g)[tid];
  float4 bb = ((const float4*)beta)[tid];
  float o0 = d0 * inv * gg.x + bb.x;
  float o1 = d1 * inv * gg.y + bb.y;
  float o2 = d2 * inv * gg.z + bb.z;
  float o3 = d3 * inv * gg.w + bb.w;
  if (OUTF32 == 0) {
    ushort4 w; w.x = f2b(o0); w.y = f2b(o1); w.z = f2b(o2); w.w = f2b(o3);
    ((ushort4*)((unsigned short*)out_ + (size_t)row * ND))[tid] = w;
  } else {
    float4 ov; ov.x = o0; ov.y = o1; ov.z = o2; ov.w = o3;
    ((float4*)((float*)out_ + (size_t)row * ND))[tid] = ov;
  }
}

// ---------------- launch ----------------

extern "C" void kernel_launch(void* const* d_in, const int* in_sizes, int n_in,
                              void* d_out, int out_size, void* d_ws, size_t ws_size,
                              hipStream_t stream)
{
  (void)in_sizes; (void)n_in; (void)out_size; (void)ws_size;
  const float* x   = (const float*)d_in[0];
  const float* Wq  = (const float*)d_in[1];
  const float* bq  = (const float*)d_in[2];
  const float* Wk  = (const float*)d_in[3];
  const float* bk  = (const float*)d_in[4];
  const float* Wv  = (const float*)d_in[5];
  const float* bv  = (const float*)d_in[6];
  const float* Wo  = (const float*)d_in[7];
  const float* bo  = (const float*)d_in[8];
  const float* g1  = (const float*)d_in[9];
  const float* be1 = (const float*)d_in[10];
  const float* W1  = (const float*)d_in[11];
  const float* b1  = (const float*)d_in[12];
  const float* W2  = (const float*)d_in[13];
  const float* b2  = (const float*)d_in[14];
  const float* g2  = (const float*)d_in[15];
  const float* be2 = (const float*)d_in[16];

  char* ws = (char*)d_ws;
  const size_t MB = 1ull << 20;
  unsigned short* x_bf  = (unsigned short*)(ws);             // 16 MiB, alive until LN1
  unsigned short* qkv   = (unsigned short*)(ws + 16 * MB);   // 48 MiB, dead after attn
  unsigned short* aout  = (unsigned short*)(ws + 16 * MB);   // 16 MiB bf16, overlays qkv (after attn)
  unsigned short* ff1   = (unsigned short*)(ws);             // 64 MiB, overlays x_bf+qkv (after LN1)
  unsigned short* ctx   = (unsigned short*)(ws + 64 * MB);   // 16 MiB, dead after out-proj
  unsigned short* h_bf  = (unsigned short*)(ws + 64 * MB);   // 16 MiB, overlays ctx
  unsigned short* Wqkvt = (unsigned short*)(ws + 80 * MB);   // 6 MiB
  unsigned short* Wot   = (unsigned short*)(ws + 86 * MB);   // 2 MiB
  unsigned short* W1t   = (unsigned short*)(ws + 88 * MB);   // 8 MiB
  unsigned short* W2t   = (unsigned short*)(ws + 96 * MB);   // 8 MiB
  float*          bqkv  = (float*)(ws + 104 * MB);           // 12 KiB
  unsigned short* ffout = (unsigned short*)(ws + 105 * MB);  // 16 MiB bf16
  unsigned short* vtg   = (unsigned short*)(ws + 121 * MB);  // 16 MiB (keeps x_bf alive)

  // fused prep: cvt + all weight transposes + bias pack (one launch)
  prep_all<<<PREP_NBLK, 256, 0, stream>>>(x, x_bf, Wq, Wk, Wv, Wqkvt,
                                          Wo, Wot, W1, W1t, W2, W2t,
                                          bq, bk, bv, bqkv);

  // QKV projection (q pre-scaled into log2 domain): 768 blocks (3 exact CU-waves)
  gemm_bt<0><<<(NM / 256) * (3072 / 128), 512, 0, stream>>>(x_bf, Wqkvt, bqkv, qkv, NM, 3072, 1024);
  // V transpose
  transpose_v<<<dim3(64, 2, 64), dim3(32, 8), 0, stream>>>(qkv, vtg);
  // attention (QBLK=256, 8 waves x 2 subtiles)
  attn_fwd<<<512, 512, 0, stream>>>(qkv, vtg, ctx);
  // output projection -> bf16: 256 blocks (1 exact CU-wave)
  gemm_bt<0><<<(NM / 256) * (1024 / 128), 512, 0, stream>>>(ctx, Wot, bo, aout, NM, 1024, 1024);
  // h = LN(x + attn_out) -> bf16 (ctx dead; h_bf overlays it)
  ln_fused<0><<<NM, 256, 0, stream>>>(x_bf, aout, g1, be1, h_bf);
  // FFN1 with tanh: 256x256 tile BK=64, 512 blocks
  gemm256<2><<<(NM / 256) * (4096 / 256), 512, 0, stream>>>(h_bf, W1t, b1, ff1, NM, 4096, 1024);
  // FFN2 -> bf16: 256 blocks (1 exact CU-wave)
  gemm_bt<0><<<(NM / 256) * (1024 / 128), 512, 0, stream>>>(ff1, W2t, b2, ffout, NM, 1024, 4096);
  // out = LN(h + ff) -> f32
  ln_fused<1><<<NM, 256, 0, stream>>>(h_bf, ffout, g2, be2, (float*)d_out);
}